// Round 4
// baseline (1806.983 us; speedup 1.0000x reference)
//
#include <hip/hip_runtime.h>

#define NB 512
#define T 128
#define NS 32
#define NC 16
#define NSC 48
#define PF 52   // pad stride for sF, sW, sQt
#define PV 36   // pad stride for sV
#define PK 36   // pad stride for sKt

__device__ __forceinline__ float4 ld4(const float* p) { return *(const float4*)p; }
__device__ __forceinline__ void st4(float* p, float4 v) { *(float4*)p = v; }
__device__ __forceinline__ void fma4(float4& a, float s, float4 f) {
    a.x = fmaf(s, f.x, a.x); a.y = fmaf(s, f.y, a.y);
    a.z = fmaf(s, f.z, a.z); a.w = fmaf(s, f.w, a.w);
}
__device__ __forceinline__ float dot4(float4 a, float4 b) {
    return fmaf(a.x, b.x, fmaf(a.y, b.y, fmaf(a.z, b.z, a.w * b.w)));
}

// ================= backward Riccati (+ cost constant kappa) =================
__global__ __launch_bounds__(256, 2)
void lqr_backward(const float* __restrict__ Q,
                  const float* __restrict__ p,
                  const float* __restrict__ A,
                  const float* __restrict__ Bm,
                  const float* __restrict__ c1,
                  const float* __restrict__ x_init,
                  float* __restrict__ Kws,
                  float* __restrict__ kws,
                  float* __restrict__ out_cost)
{
    const int b = blockIdx.x;
    const int tid = threadIdx.x;
    const int lane = tid & 63;
    const int wv = tid >> 6;

    __shared__ __align__(16) float sF[NS][PF];
    __shared__ __align__(16) float sW[NS][PF];
    __shared__ __align__(16) float sQt[NSC][PF];
    __shared__ __align__(16) float sV[NS][PV];
    __shared__ __align__(16) float sKt[NC][PK];
    __shared__ __align__(16) float sz[NS];
    __shared__ __align__(16) float sqt[NSC];
    __shared__ __align__(16) float sv[NS];
    __shared__ __align__(16) float sc1[NS];
    __shared__ __align__(16) float skt[NC];

    for (int e = tid; e < NS * NSC; e += 256) {
        int i = e / NSC, j = e % NSC;
        sF[i][j] = (j < NS) ? A[(size_t)b * NS * NS + i * NS + j]
                            : Bm[(size_t)b * NS * NC + i * NC + (j - NS)];
    }
    for (int e = tid; e < NS * NS; e += 256) sV[e >> 5][e & 31] = 0.f;
    if (tid < NS) { sv[tid] = 0.f; sc1[tid] = c1[(size_t)b * NS + tid]; }
    float kappa = 0.f, kap1 = 0.f;
    __syncthreads();

    for (int t = T - 1; t >= 0; --t) {
        const float* Qg = Q + ((size_t)b * T + t) * NSC * NSC;

        // ---- Phase A: W = V@F (tid<96, 4x4 tiles); z = v + V c1 (192..223);
        //      prefetch Qg rows 32..47 (tid<96) and p (96..143) ----
        float4 qgb0 = {0,0,0,0}, qgb1 = {0,0,0,0};
        float preg = 0.f;
        if (tid < 96) {
            const int i0 = (tid / 12) * 4, j0 = (tid % 12) * 4;
            const int i0b = NS + (tid / 12) * 2;
            qgb0 = ld4(Qg + i0b * NSC + j0);
            qgb1 = ld4(Qg + (i0b + 1) * NSC + j0);
            float4 a0 = {0,0,0,0}, a1 = a0, a2 = a0, a3 = a0;
            #pragma unroll 8
            for (int k = 0; k < NS; ++k) {
                float4 v4 = ld4(&sV[k][i0]);   // V symmetric: = V[i0:4][k]
                float4 f4 = ld4(&sF[k][j0]);
                fma4(a0, v4.x, f4); fma4(a1, v4.y, f4);
                fma4(a2, v4.z, f4); fma4(a3, v4.w, f4);
            }
            st4(&sW[i0][j0], a0); st4(&sW[i0 + 1][j0], a1);
            st4(&sW[i0 + 2][j0], a2); st4(&sW[i0 + 3][j0], a3);
        } else if (tid < 144) {
            preg = p[((size_t)b * T + t) * NSC + (tid - 96)];
        } else if (tid >= 192 && tid < 224) {
            const int i = tid - 192;
            float a = sv[i];
            #pragma unroll
            for (int j4 = 0; j4 < NS; j4 += 4)
                a += dot4(ld4(&sV[i][j4]), ld4(&sc1[j4]));
            sz[i] = a;
        }
        __syncthreads();

        // ---- Phase B: Qt rows 32..47 (tid<96, 2x4); qt (96..143);
        //      Qxx prefetch (64..127) ----
        float4 qx0 = {0,0,0,0}, qx1 = qx0, qx2 = qx0, qx3 = qx0;
        int i0c = 0, j0c = 0;
        if (tid >= 64 && tid < 128) {
            const int ct = tid - 64;
            i0c = (ct >> 3) * 4; j0c = (ct & 7) * 4;
            qx0 = ld4(Qg + (i0c + 0) * NSC + j0c);
            qx1 = ld4(Qg + (i0c + 1) * NSC + j0c);
            qx2 = ld4(Qg + (i0c + 2) * NSC + j0c);
            qx3 = ld4(Qg + (i0c + 3) * NSC + j0c);
        }
        if (tid < 96) {
            const int i0b = NS + (tid / 12) * 2, j0b = (tid % 12) * 4;
            float4 a0 = qgb0, a1 = qgb1;
            #pragma unroll 8
            for (int k = 0; k < NS; ++k) {
                float2 f2 = *(const float2*)&sF[k][i0b];
                float4 w4 = ld4(&sW[k][j0b]);
                fma4(a0, f2.x, w4); fma4(a1, f2.y, w4);
            }
            st4(&sQt[i0b][j0b], a0); st4(&sQt[i0b + 1][j0b], a1);
        } else if (tid < 144) {
            const int j = tid - 96;
            float a = preg;
            #pragma unroll 8
            for (int k = 0; k < NS; ++k) a = fmaf(sF[k][j], sz[k], a);
            sqt[j] = a;
        }
        __syncthreads();

        // ---- Phase C: wave0 GJ; Qxx (64..127, 4x4); kap1 (tid 224) ----
        if (wv == 0) {
            float R[NC];
            if (lane < NC) {
                #pragma unroll
                for (int i = 0; i < NC; ++i) R[i] = sQt[NS + i][NS + lane];
            } else if (lane < NSC) {
                #pragma unroll
                for (int i = 0; i < NC; ++i) R[i] = sQt[NS + i][lane - NC];
            } else if (lane == NSC) {
                #pragma unroll
                for (int i = 0; i < NC; ++i) R[i] = sqt[NS + i];
            } else {
                #pragma unroll
                for (int i = 0; i < NC; ++i) R[i] = 0.f;
            }
            #pragma unroll
            for (int k = 0; k < NC; ++k) {
                float pk = __shfl(R[k], k, 64);
                float inv = 1.0f / pk;
                float tm = R[k] * inv;
                #pragma unroll
                for (int i = 0; i < NC; ++i) {
                    if (i == k) continue;
                    float cki = __shfl(R[i], k, 64);
                    R[i] = fmaf(-tm, cki, R[i]);
                }
                R[k] = tm;
            }
            if (lane >= NC && lane < NSC) {
                const int cc = lane - NC;
                #pragma unroll
                for (int i = 0; i < NC; ++i) sKt[i][cc] = -R[i];
            } else if (lane == NSC) {
                #pragma unroll
                for (int i = 0; i < NC; ++i) skt[i] = -R[i];
            }
        } else if (tid < 128) {
            float4 a0 = qx0, a1 = qx1, a2 = qx2, a3 = qx3;
            #pragma unroll 8
            for (int k = 0; k < NS; ++k) {
                float4 f4 = ld4(&sF[k][i0c]);
                float4 w4 = ld4(&sW[k][j0c]);
                fma4(a0, f4.x, w4); fma4(a1, f4.y, w4);
                fma4(a2, f4.z, w4); fma4(a3, f4.w, w4);
            }
            st4(&sQt[i0c][j0c], a0); st4(&sQt[i0c + 1][j0c], a1);
            st4(&sQt[i0c + 2][j0c], a2); st4(&sQt[i0c + 3][j0c], a3);
        } else if (tid == 224) {
            float a = 0.f;
            for (int i = 0; i < NS; ++i) a = fmaf(sc1[i], sv[i] + sz[i], a);
            kap1 = 0.5f * a;
        }
        __syncthreads();

        // ---- Phase D: V (tid<64, 4x4); v (64..95); K->ws (96..159);
        //      k->ws (160..175); kappa (224) ----
        if (tid < 64) {
            const int i0 = (tid >> 3) * 4, j0 = (tid & 7) * 4;
            float4 a0 = ld4(&sQt[i0][j0]),     a1 = ld4(&sQt[i0 + 1][j0]);
            float4 a2 = ld4(&sQt[i0 + 2][j0]), a3 = ld4(&sQt[i0 + 3][j0]);
            #pragma unroll
            for (int k = 0; k < NC; ++k) {
                float4 q4 = ld4(&sQt[NS + k][i0]);  // Qxu[i0:4][k]
                float4 k4 = ld4(&sKt[k][j0]);
                fma4(a0, q4.x, k4); fma4(a1, q4.y, k4);
                fma4(a2, q4.z, k4); fma4(a3, q4.w, k4);
            }
            st4(&sV[i0][j0], a0); st4(&sV[i0 + 1][j0], a1);
            st4(&sV[i0 + 2][j0], a2); st4(&sV[i0 + 3][j0], a3);
        } else if (tid < 96) {
            const int j = tid - 64;
            float a = sqt[j];
            #pragma unroll
            for (int k = 0; k < NC; ++k) a = fmaf(sQt[NS + k][j], skt[k], a);
            sv[j] = a;
        } else if (tid < 160) {
            float4* Kg4 = (float4*)(Kws + ((size_t)b * T + t) * NC * NS);
            const int e = (tid - 96) * 2;
            Kg4[e]     = ld4(&sKt[e >> 3][(e & 7) * 4]);
            Kg4[e + 1] = ld4(&sKt[(e + 1) >> 3][((e + 1) & 7) * 4]);
        } else if (tid < 176) {
            kws[((size_t)b * T + t) * NC + (tid - 160)] = skt[tid - 160];
        } else if (tid == 224) {
            float s2 = 0.f;
            for (int i = 0; i < NC; ++i) s2 = fmaf(sqt[NS + i], skt[i], s2);
            kappa += kap1 + 0.5f * s2;
        }
        __syncthreads();
    }

    // ---- epilogue: cost = 0.5 x0^T V0 x0 + v0.x0 + kappa ----
    if (tid < NS) sz[tid] = x_init[(size_t)b * NS + tid];
    __syncthreads();
    if (tid < NS) {
        float y = 0.f;
        #pragma unroll
        for (int j4 = 0; j4 < NS; j4 += 4)
            y += dot4(ld4(&sV[tid][j4]), ld4(&sz[j4]));
        sqt[tid] = sz[tid] * (0.5f * y + sv[tid]);
    }
    __syncthreads();
    if (tid == 224) {
        float cst = kappa;
        for (int i = 0; i < NS; ++i) cst += sqt[i];
        out_cost[b] = cst;
    }
}

// ================= forward rollout: fused z-chain, no Q =================
// z_s = [F; M_s] z_{s-1} + [c1; m_s],  M_s = K_s F,  m_s = K_s c1 + k_s.
// wave0: chain (1 broadcast round/step); waves1-3: 3-stage K->M pipeline.
__global__ __launch_bounds__(256, 2)
void lqr_forward(const float* __restrict__ x_init,
                 const float* __restrict__ A,
                 const float* __restrict__ Bm,
                 const float* __restrict__ c1,
                 const float* __restrict__ Kws,
                 const float* __restrict__ kws,
                 float* __restrict__ out_x,
                 float* __restrict__ out_u)
{
    const int b = blockIdx.x;
    const int tid = threadIdx.x;
    const int lane = tid & 63;
    const int wv = tid >> 6;

    __shared__ __align__(16) float sKT[2][4][32][20];  // K^T per step: [k][r]
    __shared__ __align__(16) float sM[2][4][16][52];
    __shared__ float sm[2][4][16];
    __shared__ float skv[2][4][16];
    __shared__ __align__(16) float sFf[NS][PF];
    __shared__ float sc1f[NS];

    for (int e = tid; e < NS * NSC; e += 256) {
        int i = e / NSC, j = e % NSC;
        sFf[i][j] = (j < NS) ? A[(size_t)b * NS * NS + i * NS + j]
                             : Bm[(size_t)b * NS * NC + i * NC + (j - NS)];
    }
    if (tid < NS) sc1f[tid] = c1[(size_t)b * NS + tid];

    float c[48];
    float z = 0.f, cr = 0.f;
    if (wv == 0) {
        if (lane < NS) {
            const float* Ar = A + (size_t)b * NS * NS + lane * NS;
            const float* Br = Bm + (size_t)b * NS * NC + lane * NC;
            #pragma unroll
            for (int g = 0; g < 8; ++g) {
                float4 v = ld4(Ar + 4 * g);
                c[4*g] = v.x; c[4*g+1] = v.y; c[4*g+2] = v.z; c[4*g+3] = v.w;
            }
            #pragma unroll
            for (int g = 0; g < 4; ++g) {
                float4 v = ld4(Br + 4 * g);
                c[32+4*g] = v.x; c[33+4*g] = v.y; c[34+4*g] = v.z; c[35+4*g] = v.w;
            }
            cr = c1[(size_t)b * NS + lane];
            z = x_init[(size_t)b * NS + lane];
        } else if (lane < NSC) {
            const float* Kr = Kws + (size_t)b * T * NC * NS + (lane - NS) * NS;
            #pragma unroll
            for (int g = 0; g < 8; ++g) {
                float4 v = ld4(Kr + 4 * g);
                c[4*g] = v.x; c[4*g+1] = v.y; c[4*g+2] = v.z; c[4*g+3] = v.w;
            }
            #pragma unroll
            for (int j = 32; j < 48; ++j) c[j] = 0.f;
            cr = kws[(size_t)b * T * NC + (lane - NS)];  // k_0
        } else {
            #pragma unroll
            for (int j = 0; j < 48; ++j) c[j] = 0.f;
        }
    }
    __syncthreads();

    for (int i = 0; i < 34; ++i) {
        if (wv == 0) {
            if (i == 0) {
                // z_0: lanes<32 = x0; lanes 32..47: u0 = K0 x0 + k0
                float acc[4] = {0,0,0,0};
                #pragma unroll
                for (int j = 0; j < NS; ++j) {
                    float zb = __shfl(z, j, 64);
                    acc[j & 3] = fmaf(c[j], zb, acc[j & 3]);
                }
                float u0 = (acc[0] + acc[1]) + (acc[2] + acc[3]) + cr;
                if (lane >= NS && lane < NSC) z = u0;
                if (lane < NS) out_x[((size_t)b * T) * NS + lane] = z;
                else if (lane < NSC) out_u[((size_t)b * T) * NC + (lane - NS)] = z;
            } else if (i >= 2) {
                const int cch = i - 2, ring = cch & 1;
                #pragma unroll
                for (int sl = 0; sl < 4; ++sl) {
                    const int s = cch * 4 + sl;
                    if (s == 0) continue;
                    if (lane >= NS && lane < NSC) {
                        const float* mr = &sM[ring][sl][lane - NS][0];
                        #pragma unroll
                        for (int g = 0; g < 12; ++g) {
                            float4 v = ld4(mr + 4 * g);
                            c[4*g] = v.x; c[4*g+1] = v.y; c[4*g+2] = v.z; c[4*g+3] = v.w;
                        }
                        cr = sm[ring][sl][lane - NS];
                    }
                    float acc[4] = {0,0,0,0};
                    #pragma unroll
                    for (int j = 0; j < NSC; ++j) {
                        float zb = __shfl(z, j, 64);
                        acc[j & 3] = fmaf(c[j], zb, acc[j & 3]);
                    }
                    float zn = (acc[0] + acc[1]) + (acc[2] + acc[3]) + cr;
                    if (lane < NSC) z = zn;
                    if (lane < NS) out_x[((size_t)b * T + s) * NS + lane] = z;
                    else if (lane < NSC) out_u[((size_t)b * T + s) * NC + (lane - NS)] = z;
                }
            }
        } else {
            const int ct = tid - 64;
            if (i < 32) {   // stage K,k chunk i (transposed into LDS)
                const int ring = i & 1;
                const float* Kg = Kws + ((size_t)b * T + i * 4) * NC * NS;
                #pragma unroll
                for (int rep = 0; rep < 3; ++rep) {
                    const int idx = ct + rep * 192;
                    if (idx < 512) {
                        float4 kv = ld4(Kg + idx * 4);
                        const int sl = idx >> 7, rem = idx & 127;
                        const int r = rem >> 3, c4 = (rem & 7) * 4;
                        sKT[ring][sl][c4 + 0][r] = kv.x;
                        sKT[ring][sl][c4 + 1][r] = kv.y;
                        sKT[ring][sl][c4 + 2][r] = kv.z;
                        sKT[ring][sl][c4 + 3][r] = kv.w;
                    }
                }
                if (ct < 16) {
                    float4 kv = ld4(kws + ((size_t)b * T + i * 4 + (ct >> 2)) * NC + (ct & 3) * 4);
                    const int sl = ct >> 2, c4 = (ct & 3) * 4;
                    skv[ring][sl][c4 + 0] = kv.x; skv[ring][sl][c4 + 1] = kv.y;
                    skv[ring][sl][c4 + 2] = kv.z; skv[ring][sl][c4 + 3] = kv.w;
                }
            }
            if (i >= 1 && i <= 32) {   // compute M,m chunk i-1
                const int cch = i - 1, ring = cch & 1;
                if (ct < 96) {
                    const int sl = ct / 24, rem = ct % 24;
                    const int r0 = (rem / 6) * 4, j0 = (rem % 6) * 8;
                    float4 a00 = {0,0,0,0}, a01 = a00, a10 = a00, a11 = a00;
                    float4 a20 = a00, a21 = a00, a30 = a00, a31 = a00;
                    #pragma unroll 8
                    for (int k = 0; k < NS; ++k) {
                        float4 kk = ld4(&sKT[ring][sl][k][r0]);   // K[s][r0:4][k]
                        float4 f0 = ld4(&sFf[k][j0]);
                        float4 f1 = ld4(&sFf[k][j0 + 4]);
                        fma4(a00, kk.x, f0); fma4(a01, kk.x, f1);
                        fma4(a10, kk.y, f0); fma4(a11, kk.y, f1);
                        fma4(a20, kk.z, f0); fma4(a21, kk.z, f1);
                        fma4(a30, kk.w, f0); fma4(a31, kk.w, f1);
                    }
                    st4(&sM[ring][sl][r0 + 0][j0], a00); st4(&sM[ring][sl][r0 + 0][j0 + 4], a01);
                    st4(&sM[ring][sl][r0 + 1][j0], a10); st4(&sM[ring][sl][r0 + 1][j0 + 4], a11);
                    st4(&sM[ring][sl][r0 + 2][j0], a20); st4(&sM[ring][sl][r0 + 2][j0 + 4], a21);
                    st4(&sM[ring][sl][r0 + 3][j0], a30); st4(&sM[ring][sl][r0 + 3][j0 + 4], a31);
                } else if (ct < 160) {
                    const int id = ct - 96, sl = id >> 4, r = id & 15;
                    float a = skv[ring][sl][r];
                    #pragma unroll 8
                    for (int k = 0; k < NS; ++k)
                        a = fmaf(sKT[ring][sl][k][r], sc1f[k], a);
                    sm[ring][sl][r] = a;
                }
            }
        }
        __syncthreads();
    }
}

extern "C" void kernel_launch(void* const* d_in, const int* in_sizes, int n_in,
                              void* d_out, int out_size, void* d_ws, size_t ws_size,
                              hipStream_t stream) {
    const float* x_init = (const float*)d_in[0];
    const float* Q      = (const float*)d_in[1];
    const float* p      = (const float*)d_in[2];
    const float* A      = (const float*)d_in[3];
    const float* Bm     = (const float*)d_in[4];
    const float* c1     = (const float*)d_in[5];

    float* out      = (float*)d_out;
    float* out_x    = out;
    float* out_u    = out + (size_t)NB * T * NS;
    float* out_cost = out + (size_t)NB * T * (NS + NC);

    float* Kws = (float*)d_ws;
    float* kws = Kws + (size_t)NB * T * NC * NS;

    lqr_backward<<<NB, 256, 0, stream>>>(Q, p, A, Bm, c1, x_init, Kws, kws, out_cost);
    lqr_forward<<<NB, 256, 0, stream>>>(x_init, A, Bm, c1, Kws, kws, out_x, out_u);
}